// Round 11
// baseline (194.633 us; speedup 1.0000x reference)
//
#include <hip/hip_runtime.h>
#include <hip/hip_fp16.h>

// Submanifold sparse 3D conv, k=3, pad=1, no bias.
// Grid: 41 x 1024 x 1024, N=300000 active sites, C_in=32, C_out=64, fp32 I/O.
//
// R17 = R16 resubmitted verbatim (R16 hit a GPU-acquisition timeout, never
// ran). Single-variable A/B vs R8 (conv 63us) must be preserved.
// R16 = R8 chassis with PPW 16 -> 32 (fat waves). Rationale: R8's conv is
// per-wave latency-chain bound (all pipes <30%); R13 (residency+), R14
// (persistent prefetch), R15 (exact bitmap) all regressed. The chain's
// fixed latency stalls (idx/probe/lookup/stage) are paid once per WAVE, so
// doubling points/wave halves the per-point latency cost:
//  - 2 lanes/point, 13 full probe rounds (t=6 partial round gone);
//  - octet bitmap REVERTED from R15 (5.25MB voxel bitmap broke L2: FETCH
//    52->100MB); 656KB octet bitmap is L2-cheap;
//  - 2-pass center MFMA sharing B-fragments (8 MFMA / 4 B-loads);
//  - meta widened to 10 bits (pt 5 bits); hlist = ni<<10 | pt<<5 | k;
//  - blocks = 128 threads (2 waves), same 4688-block grid, LDS 26.5KB/block.
// Predicted: conv ~48-55us, FETCH ~52MB, WRITE 75MB (>80 = spill alarm),
// VGPR 70-100. If flat/regressed -> resubmit R8, conclude.

#define ZD 41
#define YD 1024
#define XD 1024

constexpr int CIN = 32;
constexpr int COUT = 64;
constexpr unsigned HASH_BITS = 20;               // 2^20 slots, load ~0.29
constexpr unsigned CAP = 1u << HASH_BITS;
constexpr unsigned GROUP_BITS = HASH_BITS - 3;   // octet groups
constexpr unsigned long long EMPTY = ~0ull;
constexpr unsigned NVOX = ZD * YD * XD;
constexpr unsigned NOCT = NVOX / 8;
constexpr unsigned BMWORDS = (NOCT + 31) / 32;   // 656 KB (bit=1: EMPTY)
constexpr int PPW = 32;                          // points per wave (was 16)
constexpr int CAND_CAP = 128;                    // candidate slots per wave
constexpr int HROWS = 64;                        // staged hit rows per wave
constexpr int WPACK_N = 27 * 4 * 64;             // uint4 entries

typedef _Float16 half2_t __attribute__((ext_vector_type(2)));
typedef _Float16 half8_t __attribute__((ext_vector_type(8)));
typedef __fp16 pk2_t __attribute__((ext_vector_type(2)));   // cvt_pkrtz result type
typedef float floatx4 __attribute__((ext_vector_type(4)));

union H2U { pk2_t p; half2_t h; unsigned u; };
union H8U { half8_t v; half2_t h2[4]; pk2_t p2[4]; uint4 u4; };

// --- packed per-round neighbor-delta immediates -----------------------------
// Round t (0..12), lane slot j2 = lane&1 handles off = 2t+j2 (0..25),
// k = off + (off>=13). Field (6 bits): (dx+1) | (dy+1)<<2 | (dz+1)<<4.
__host__ __device__ constexpr unsigned pack6(int k) {
    return (unsigned)((k % 3) | (((k / 3) % 3) << 2) | ((k / 9) << 4));
}
__host__ __device__ constexpr unsigned cw2_round(int t) {
    unsigned w = 0;
    for (int j2 = 0; j2 < 2; ++j2) {
        int off = 2 * t + j2;                    // all 26 offs covered, no tail
        int k = off + (off >= 13);
        w |= pack6(k) << (6 * j2);
    }
    return w;
}

__device__ __forceinline__ unsigned hash_slot(unsigned lin) {
    unsigned gh = ((lin >> 3) * 2654435761u) >> (32 - GROUP_BITS);
    return (gh << 3) | (lin & 7u);
}

__global__ void build_hash_kernel(const int4* __restrict__ idx, int n,
                                  unsigned long long* __restrict__ table,
                                  unsigned* __restrict__ bitmap,
                                  const float* __restrict__ weight,
                                  uint4* __restrict__ wpack) {
    int i = blockIdx.x * blockDim.x + threadIdx.x;
    // --- pack fp32 weights -> f16 pairs: wpack[(k*4+g)*64+co] = 8 f16 (ci 8g..8g+7)
    if (i < WPACK_N) {
        int co = i & 63, g = (i >> 6) & 3, k = i >> 8;
        const float* b = weight + k * (CIN * COUT) + (8 * g) * COUT + co;
        H2U p0, p1, p2, p3;
        p0.p = __builtin_amdgcn_cvt_pkrtz(b[0 * COUT], b[1 * COUT]);
        p1.p = __builtin_amdgcn_cvt_pkrtz(b[2 * COUT], b[3 * COUT]);
        p2.p = __builtin_amdgcn_cvt_pkrtz(b[4 * COUT], b[5 * COUT]);
        p3.p = __builtin_amdgcn_cvt_pkrtz(b[6 * COUT], b[7 * COUT]);
        wpack[i] = make_uint4(p0.u, p1.u, p2.u, p3.u);
    }
    if (i >= n) return;
    int4 c = idx[i];                             // (b, z, y, x)
    unsigned lin = (unsigned)(c.y * (YD * XD) + c.z * XD + c.w);
    unsigned g = lin >> 3;
    atomicAnd(&bitmap[g >> 5], ~(1u << (g & 31u)));   // clear bit = occupied
    unsigned long long packed = ((unsigned long long)(unsigned)i << 32) | (unsigned long long)lin;
    unsigned h = hash_slot(lin);
    while (atomicCAS(&table[h], EMPTY, packed) != EMPTY) {
        h = (h + 1) & (CAP - 1);                 // coords unique -> no dup check
    }
}

__device__ __forceinline__ int lookup(const unsigned long long* __restrict__ table,
                                      unsigned lin) {
    unsigned h = hash_slot(lin);
    while (true) {
        unsigned long long s = table[h];
        if (s == EMPTY) return -1;
        if ((unsigned)s == lin) return (int)(s >> 32);
        h = (h + 1) & (CAP - 1);
    }
}

// fp32 broadcast fallback tap (rare overflow paths) into LDS accum.
__device__ __forceinline__ void fb_tap(const float* __restrict__ feat,
                                       const float* __restrict__ weight,
                                       float* __restrict__ acc,
                                       int ni, int pt, int k, int lane) {
    const float4* fr = (const float4*)(feat + (size_t)ni * CIN);
    const float* wk = weight + k * (CIN * COUT) + lane;
    float s0 = 0.f, s1 = 0.f, s2 = 0.f, s3 = 0.f;
#pragma unroll
    for (int q = 0; q < 8; ++q) {
        float4 f = fr[q];
        s0 = fmaf(f.x, wk[(4 * q + 0) * COUT], s0);
        s1 = fmaf(f.y, wk[(4 * q + 1) * COUT], s1);
        s2 = fmaf(f.z, wk[(4 * q + 2) * COUT], s2);
        s3 = fmaf(f.w, wk[(4 * q + 3) * COUT], s3);
    }
    acc[pt * COUT + lane] += (s0 + s1) + (s2 + s3);
}

__global__ __launch_bounds__(128, 4) void subm_conv_kernel(
    const float* __restrict__ feat, const int4* __restrict__ idx,
    const float* __restrict__ weight, const uint4* __restrict__ wpack,
    const unsigned long long* __restrict__ table,
    const unsigned* __restrict__ bitmap, float* __restrict__ out, int n) {
    __shared__ unsigned rows_l[2][HROWS * 16];          // 8 KB: f16 rows
    __shared__ float accum_l[2][PPW * COUT];            // 16 KB
    __shared__ unsigned long long cand_l[2][CAND_CAP];  // 2 KB
    __shared__ unsigned hlist_l[2][HROWS];              // 512 B

    int wid = threadIdx.x >> 6;                         // 0..1
    int lane = threadIdx.x & 63;
    int p0 = (blockIdx.x * 2 + wid) * PPW;
    if (p0 >= n) return;
    int np = min(PPW, n - p0);

    // --- coords: 2 lanes per point
    int pt = lane >> 1;                                 // 0..31
    int4 c = idx[p0 + (pt < np ? pt : 0)];

    // --- bitmap words for 13 probe rounds (independent, issued early)
    int sh6 = (lane & 1) * 6;
    bool ptok = (pt < np);
    unsigned nlin_t[13];
    unsigned bmw[13];
    bool try_t[13];
#pragma unroll
    for (int t = 0; t < 13; ++t) {
        unsigned w = (cw2_round(t) >> sh6) & 63u;
        int nz = c.y + (int)(w >> 4) - 1;
        int ny = c.z + (int)((w >> 2) & 3u) - 1;
        int nx = c.w + (int)(w & 3u) - 1;
        bool ok = ptok && (unsigned)nz < (unsigned)ZD && (unsigned)ny < (unsigned)YD &&
                  (unsigned)nx < (unsigned)XD;
        unsigned nlin = ok ? ((((unsigned)nz << 10) + (unsigned)ny) << 10) + (unsigned)nx : 0u;
        nlin_t[t] = nlin;
        try_t[t] = ok;
        bmw[t] = ok ? bitmap[nlin >> 8] : ~0u;          // octet bitmap, bit=1 empty
    }

    // --- center tap via MFMA f16, 2 passes of 16 rows; B-fragments shared
    int arow = lane & 15, aq = lane >> 4;               // aq 0..3
    H8U bfrag[4];
#pragma unroll
    for (int ch = 0; ch < 4; ++ch) {
        bfrag[ch].u4 = wpack[(13 * 4 + aq) * 64 + ch * 16 + (lane & 15)];
    }
#pragma unroll
    for (int p = 0; p < 2; ++p) {
        int r0 = p * 16 + arow;
        int rowp = p0 + (r0 < np ? r0 : np - 1);
        float4 af0 = *(const float4*)(feat + (size_t)rowp * CIN + aq * 8);
        float4 af1 = *(const float4*)(feat + (size_t)rowp * CIN + aq * 8 + 4);
        H8U afrag;
        afrag.p2[0] = __builtin_amdgcn_cvt_pkrtz(af0.x, af0.y);
        afrag.p2[1] = __builtin_amdgcn_cvt_pkrtz(af0.z, af0.w);
        afrag.p2[2] = __builtin_amdgcn_cvt_pkrtz(af1.x, af1.y);
        afrag.p2[3] = __builtin_amdgcn_cvt_pkrtz(af1.z, af1.w);
#pragma unroll
        for (int ch = 0; ch < 4; ++ch) {
            floatx4 z = {0.f, 0.f, 0.f, 0.f};
            floatx4 cacc =
                __builtin_amdgcn_mfma_f32_16x16x32_f16(afrag.v, bfrag[ch].v, z, 0, 0, 0);
            // C row = p*16 + (lane>>4)*4 + r, col = ch*16 + (lane&15)
#pragma unroll
            for (int r = 0; r < 4; ++r) {
                accum_l[wid][(p * 16 + (lane >> 4) * 4 + r) * COUT + ch * 16 + (lane & 15)] =
                    cacc[r];
            }
        }
    }

    // --- candidate compaction (bitmap-passing probes) into LDS
    int cbase = 0;
    unsigned ovmask = 0;
#pragma unroll
    for (int t = 0; t < 13; ++t) {
        unsigned nlin = nlin_t[t];
        bool candq = try_t[t] && !((bmw[t] >> ((nlin >> 3) & 31u)) & 1u);
        unsigned long long m = __ballot(candq);
        if (candq) {
            int r = cbase + __popcll(m & ((1ull << lane) - 1ull));
            int off = (lane & 1) + 2 * t;
            int k = off + (off >= 13);
            if (r < CAND_CAP) {
                cand_l[wid][r] = ((unsigned long long)(((unsigned)pt << 5) | (unsigned)k) << 32)
                                 | (unsigned long long)nlin;
            } else {
                ovmask |= 1u << t;
            }
        }
        cbase += __popcll(m);
    }
    int ncand = cbase < CAND_CAP ? cbase : CAND_CAP;
    __asm__ __volatile__("s_waitcnt lgkmcnt(0)" ::: "memory");

    // --- parallel lookups: lane j resolves candidate j (2 rounds, <=128)
    int hitbase = 0;
    int hni[2];
    unsigned hmeta[2];
    bool hov[2] = {false, false};
#pragma unroll
    for (int sub = 0; sub < 2; ++sub) {
        int j = sub * 64 + lane;
        int ni = -1;
        unsigned meta = 0;
        if (j < ncand) {
            unsigned long long e = cand_l[wid][j];
            meta = (unsigned)(e >> 32);              // 10 bits: pt<<5 | k
            ni = lookup(table, (unsigned)e);
        }
        unsigned long long m = __ballot(ni >= 0);
        if (ni >= 0) {
            int hr = hitbase + __popcll(m & ((1ull << lane) - 1ull));
            if (hr < HROWS) {
                hlist_l[wid][hr] = ((unsigned)ni << 10) | meta;
            } else {
                hov[sub] = true; hni[sub] = ni; hmeta[sub] = meta;
            }
        }
        hitbase += __popcll(m);
    }
    int hits = hitbase < HROWS ? hitbase : HROWS;
    __asm__ __volatile__("s_waitcnt lgkmcnt(0)" ::: "memory");

    // --- stage all hit rows as f16 (lane e handles row e>>2, seg e&3 = 8 ci)
    for (int e = lane; e < hits * 4; e += 64) {
        int r = e >> 2, s = e & 3;
        int ni = (int)(hlist_l[wid][r] >> 10);
        float4 u = *(const float4*)(feat + (size_t)ni * CIN + s * 8);
        float4 v = *(const float4*)(feat + (size_t)ni * CIN + s * 8 + 4);
        H2U q0, q1, q2, q3;
        q0.p = __builtin_amdgcn_cvt_pkrtz(u.x, u.y);
        q1.p = __builtin_amdgcn_cvt_pkrtz(u.z, u.w);
        q2.p = __builtin_amdgcn_cvt_pkrtz(v.x, v.y);
        q3.p = __builtin_amdgcn_cvt_pkrtz(v.z, v.w);
        *(uint4*)&rows_l[wid][r * 16 + s * 4] = make_uint4(q0.u, q1.u, q2.u, q3.u);
    }
    __asm__ __volatile__("s_waitcnt vmcnt(0) lgkmcnt(0)" ::: "memory");

    // --- hit taps: lane = co; 4x(ds_read_b128 + uint4 weight load + 4 fdot2)
    for (int j = 0; j < hits; ++j) {
        unsigned meta = hlist_l[wid][j] & 1023u;
        int k = (int)(meta & 31u);
        int pt2 = (int)(meta >> 5);                  // 0..31
        float s = 0.f;
#pragma unroll
        for (int g = 0; g < 4; ++g) {
            H8U fv, wv;
            fv.u4 = *(const uint4*)&rows_l[wid][j * 16 + g * 4];
            wv.u4 = wpack[(k * 4 + g) * 64 + lane];
            s = __builtin_amdgcn_fdot2(fv.h2[0], wv.h2[0], s, false);
            s = __builtin_amdgcn_fdot2(fv.h2[1], wv.h2[1], s, false);
            s = __builtin_amdgcn_fdot2(fv.h2[2], wv.h2[2], s, false);
            s = __builtin_amdgcn_fdot2(fv.h2[3], wv.h2[3], s, false);
        }
        accum_l[wid][pt2 * COUT + lane] += s;
    }

    // --- rare overflow paths (fp32 broadcast fallback)
    if (__builtin_expect(cbase > CAND_CAP, 0)) {
#pragma unroll
        for (int t = 0; t < 13; ++t) {
            unsigned long long m = __ballot((ovmask >> t) & 1u);
            while (m) {
                int src = __ffsll((unsigned long long)m) - 1;
                m &= m - 1;
                unsigned nlin = __shfl(nlin_t[t], src);
                int pt2 = src >> 1;
                int off = (src & 1) + 2 * t;
                int k = off + (off >= 13);
                int ni = lookup(table, nlin);
                if (ni >= 0) fb_tap(feat, weight, accum_l[wid], ni, pt2, k, lane);
            }
        }
    }
    if (__builtin_expect(hitbase > HROWS, 0)) {
#pragma unroll
        for (int sub = 0; sub < 2; ++sub) {
            unsigned long long m = __ballot(hov[sub]);
            while (m) {
                int src = __ffsll((unsigned long long)m) - 1;
                m &= m - 1;
                int ni = __shfl(hni[sub], src);
                unsigned meta = (unsigned)__shfl((int)hmeta[sub], src);
                fb_tap(feat, weight, accum_l[wid], ni, (int)((meta >> 5) & 31u),
                       (int)(meta & 31u), lane);
            }
        }
    }
    __asm__ __volatile__("s_waitcnt lgkmcnt(0)" ::: "memory");

    // --- coalesced store pass: dwordx4 per lane
    for (int e = lane; e < np * 16; e += 64) {
        int g = e >> 4, cq = e & 15;
        floatx4 v = *(const floatx4*)&accum_l[wid][g * COUT + cq * 4];
        __builtin_nontemporal_store(v, (floatx4*)&out[(size_t)(p0 + g) * COUT + cq * 4]);
    }
}

extern "C" void kernel_launch(void* const* d_in, const int* in_sizes, int n_in,
                              void* d_out, int out_size, void* d_ws, size_t ws_size,
                              hipStream_t stream) {
    const float* feat   = (const float*)d_in[0];   // [N, 32]
    const int4*  idx    = (const int4*)d_in[1];    // [N, 4] int32 (b,z,y,x)
    const float* weight = (const float*)d_in[2];   // [27, 32, 64]
    float* out = (float*)d_out;                    // [N, 64]
    int n = in_sizes[0] / CIN;

    unsigned char* base = (unsigned char*)d_ws;
    unsigned long long* table = (unsigned long long*)base;              // 8 MB
    unsigned* bitmap = (unsigned*)(base + (size_t)CAP * 8);             // 656 KB
    uint4* wpack = (uint4*)(base + (size_t)CAP * 8 + (size_t)BMWORDS * 4);  // 108 KB

    // One memset covers table (0xFF = EMPTY) and bitmap (0xFF = all-empty).
    hipMemsetAsync(table, 0xFF, (size_t)CAP * 8 + (size_t)BMWORDS * 4, stream);

    int bwork = n > WPACK_N ? n : WPACK_N;
    int bblocks = (bwork + 255) / 256;
    build_hash_kernel<<<bblocks, 256, 0, stream>>>(idx, n, table, bitmap, weight, wpack);

    int ppb = 2 * PPW;                             // 64 points per block (2 waves)
    int cblocks = (n + ppb - 1) / ppb;
    subm_conv_kernel<<<cblocks, 128, 0, stream>>>(feat, idx, weight, wpack, table,
                                                  bitmap, out, n);
}

// Round 12
// 185.904 us; speedup vs baseline: 1.0470x; 1.0470x over previous
//
#include <hip/hip_runtime.h>
#include <hip/hip_fp16.h>

// Submanifold sparse 3D conv, k=3, pad=1, no bias.
// Grid: 41 x 1024 x 1024, N=300000 active sites, C_in=32, C_out=64, fp32 I/O.
//
// R18 = R8 chassis (best measured: conv 63us / total 185.2) with the bitmap
// at QUAD granularity (4 voxels/bit, 1.31 MB) instead of octet (8/bit, 656KB).
// History: R13 residency+ (84us), R14 persistent+prefetch (82us), R15 exact
// 1-bit/voxel bitmap (66.5us, FETCH 52->100MB: 5.25MB > 4MiB/XCD L2), R17
// fat waves (71.5us, occupancy 21%) ALL regressed -> R8 geometry is optimal;
// only the lookup phase has a quantified inefficiency left: 22.6 cand/wave
// vs 2.9 hits (87% FP from octet dilution); lookup stall = lane-max probe
// chain over ~23 lanes. Quad bitmap halves dilution (cand ~11.7/wave, failed
// lookups 20->9) while staying L2-resident. Three-line diff vs R8:
//   BMWORDS from NVOX/4 bits; build atomicAnd at (lin>>2); conv reads
//   bitmap[nlin>>7], tests bit (nlin>>2)&31. Everything else identical.
// Predicted: conv ~57-60us, FETCH ~53MB (>60 = L2 theory wrong, revert),
// WRITE 75MB, VGPR ~52, total ~180-182.

#define ZD 41
#define YD 1024
#define XD 1024

constexpr int CIN = 32;
constexpr int COUT = 64;
constexpr unsigned HASH_BITS = 20;               // 2^20 slots, load ~0.29
constexpr unsigned CAP = 1u << HASH_BITS;
constexpr unsigned GROUP_BITS = HASH_BITS - 3;   // octet groups (hash key only)
constexpr unsigned long long EMPTY = ~0ull;
constexpr unsigned NVOX = ZD * YD * XD;
constexpr unsigned NQUAD = NVOX / 4;             // quad groups (bitmap)
constexpr unsigned BMWORDS = (NQUAD + 31) / 32;  // 1.31 MB (bit=1: EMPTY)
constexpr int PPW = 16;                          // points per wave
constexpr int CAND_CAP = 96;                     // candidate slots per wave
constexpr int HROWS = 48;                        // staged hit rows per wave
constexpr int WPACK_N = 27 * 4 * 64;             // uint4 entries

typedef _Float16 half2_t __attribute__((ext_vector_type(2)));
typedef _Float16 half8_t __attribute__((ext_vector_type(8)));
typedef __fp16 pk2_t __attribute__((ext_vector_type(2)));   // cvt_pkrtz result type
typedef float floatx4 __attribute__((ext_vector_type(4)));

union H2U { pk2_t p; half2_t h; unsigned u; };
union H8U { half8_t v; half2_t h2[4]; pk2_t p2[4]; uint4 u4; };

// --- packed per-round neighbor-delta immediates -----------------------------
// Round t, lane slot j4 = lane&3 handles off = 4t+j4 (off<26), k = off+(off>=13).
// Field (6 bits): (dx+1) | (dy+1)<<2 | (dz+1)<<4.
__host__ __device__ constexpr unsigned pack6(int k) {
    return (unsigned)((k % 3) | (((k / 3) % 3) << 2) | ((k / 9) << 4));
}
__host__ __device__ constexpr unsigned cw_round(int t) {
    unsigned w = 0;
    for (int j4 = 0; j4 < 4; ++j4) {
        int off = 4 * t + j4;
        if (off < 26) {
            int k = off + (off >= 13);
            w |= pack6(k) << (6 * j4);
        }
    }
    return w;
}

__device__ __forceinline__ unsigned hash_slot(unsigned lin) {
    unsigned gh = ((lin >> 3) * 2654435761u) >> (32 - GROUP_BITS);
    return (gh << 3) | (lin & 7u);
}

__global__ void build_hash_kernel(const int4* __restrict__ idx, int n,
                                  unsigned long long* __restrict__ table,
                                  unsigned* __restrict__ bitmap,
                                  const float* __restrict__ weight,
                                  uint4* __restrict__ wpack) {
    int i = blockIdx.x * blockDim.x + threadIdx.x;
    // --- pack fp32 weights -> f16 pairs: wpack[(k*4+g)*64+co] = 8 f16 (ci 8g..8g+7)
    if (i < WPACK_N) {
        int co = i & 63, g = (i >> 6) & 3, k = i >> 8;
        const float* b = weight + k * (CIN * COUT) + (8 * g) * COUT + co;
        H2U p0, p1, p2, p3;
        p0.p = __builtin_amdgcn_cvt_pkrtz(b[0 * COUT], b[1 * COUT]);
        p1.p = __builtin_amdgcn_cvt_pkrtz(b[2 * COUT], b[3 * COUT]);
        p2.p = __builtin_amdgcn_cvt_pkrtz(b[4 * COUT], b[5 * COUT]);
        p3.p = __builtin_amdgcn_cvt_pkrtz(b[6 * COUT], b[7 * COUT]);
        wpack[i] = make_uint4(p0.u, p1.u, p2.u, p3.u);
    }
    if (i >= n) return;
    int4 c = idx[i];                             // (b, z, y, x)
    unsigned lin = (unsigned)(c.y * (YD * XD) + c.z * XD + c.w);
    unsigned q = lin >> 2;                       // quad group
    atomicAnd(&bitmap[q >> 5], ~(1u << (q & 31u)));   // clear bit = occupied
    unsigned long long packed = ((unsigned long long)(unsigned)i << 32) | (unsigned long long)lin;
    unsigned h = hash_slot(lin);
    while (atomicCAS(&table[h], EMPTY, packed) != EMPTY) {
        h = (h + 1) & (CAP - 1);                 // coords unique -> no dup check
    }
}

__device__ __forceinline__ int lookup(const unsigned long long* __restrict__ table,
                                      unsigned lin) {
    unsigned h = hash_slot(lin);
    while (true) {
        unsigned long long s = table[h];
        if (s == EMPTY) return -1;
        if ((unsigned)s == lin) return (int)(s >> 32);
        h = (h + 1) & (CAP - 1);
    }
}

// fp32 broadcast fallback tap (rare overflow paths) into LDS accum.
__device__ __forceinline__ void fb_tap(const float* __restrict__ feat,
                                       const float* __restrict__ weight,
                                       float* __restrict__ acc,
                                       int ni, int pt, int k, int lane) {
    const float4* fr = (const float4*)(feat + (size_t)ni * CIN);
    const float* wk = weight + k * (CIN * COUT) + lane;
    float s0 = 0.f, s1 = 0.f, s2 = 0.f, s3 = 0.f;
#pragma unroll
    for (int q = 0; q < 8; ++q) {
        float4 f = fr[q];
        s0 = fmaf(f.x, wk[(4 * q + 0) * COUT], s0);
        s1 = fmaf(f.y, wk[(4 * q + 1) * COUT], s1);
        s2 = fmaf(f.z, wk[(4 * q + 2) * COUT], s2);
        s3 = fmaf(f.w, wk[(4 * q + 3) * COUT], s3);
    }
    acc[pt * COUT + lane] += (s0 + s1) + (s2 + s3);
}

__global__ __launch_bounds__(256, 4) void subm_conv_kernel(
    const float* __restrict__ feat, const int4* __restrict__ idx,
    const float* __restrict__ weight, const uint4* __restrict__ wpack,
    const unsigned long long* __restrict__ table,
    const unsigned* __restrict__ bitmap, float* __restrict__ out, int n) {
    __shared__ unsigned rows_l[4][HROWS * 16];          // 12 KB: f16 rows (16 u32 each)
    __shared__ float accum_l[4][PPW * COUT];            // 16 KB
    __shared__ unsigned long long cand_l[4][CAND_CAP];  // 3 KB
    __shared__ unsigned hlist_l[4][HROWS];              // 768 B

    int wid = threadIdx.x >> 6;
    int lane = threadIdx.x & 63;
    int p0 = (blockIdx.x * 4 + wid) * PPW;
    if (p0 >= n) return;
    int np = min(PPW, n - p0);

    // --- coords: 4 lanes per point
    int pt = lane >> 2;
    int4 c = idx[p0 + (pt < np ? pt : 0)];

    // --- bitmap words for 7 probe rounds (independent, issued early)
    int sh6 = (lane & 3) * 6;
    bool ptok = (pt < np);
    unsigned nlin_t[7];
    unsigned bmw[7];
    bool try_t[7];
#pragma unroll
    for (int t = 0; t < 7; ++t) {
        unsigned w = (cw_round(t) >> sh6) & 63u;
        int nz = c.y + (int)(w >> 4) - 1;
        int ny = c.z + (int)((w >> 2) & 3u) - 1;
        int nx = c.w + (int)(w & 3u) - 1;
        bool ok = ptok && (unsigned)nz < (unsigned)ZD && (unsigned)ny < (unsigned)YD &&
                  (unsigned)nx < (unsigned)XD;
        if (t == 6) ok = ok && ((lane & 3) < 2);        // offs 26,27 don't exist
        unsigned nlin = ok ? ((((unsigned)nz << 10) + (unsigned)ny) << 10) + (unsigned)nx : 0u;
        nlin_t[t] = nlin;
        try_t[t] = ok;
        bmw[t] = ok ? bitmap[nlin >> 7] : ~0u;          // quad bitmap, bit=1 empty
    }

    // --- center tap via MFMA f16: D[pt][co] = feat[p0+pt][:] @ W13
    int arow = lane & 15, aq = lane >> 4;               // A: m=lane&15, k=aq*8+j
    int rowp = p0 + (arow < np ? arow : np - 1);
    float4 af0 = *(const float4*)(feat + (size_t)rowp * CIN + aq * 8);
    float4 af1 = *(const float4*)(feat + (size_t)rowp * CIN + aq * 8 + 4);
    H8U afrag;
    afrag.p2[0] = __builtin_amdgcn_cvt_pkrtz(af0.x, af0.y);
    afrag.p2[1] = __builtin_amdgcn_cvt_pkrtz(af0.z, af0.w);
    afrag.p2[2] = __builtin_amdgcn_cvt_pkrtz(af1.x, af1.y);
    afrag.p2[3] = __builtin_amdgcn_cvt_pkrtz(af1.z, af1.w);

    floatx4 cacc[4];
#pragma unroll
    for (int ch = 0; ch < 4; ++ch) {
        H8U bfrag;                                       // B: k=aq*8+j, n=lane&15
        bfrag.u4 = wpack[(13 * 4 + aq) * 64 + ch * 16 + (lane & 15)];
        floatx4 z = {0.f, 0.f, 0.f, 0.f};
        cacc[ch] = __builtin_amdgcn_mfma_f32_16x16x32_f16(afrag.v, bfrag.v, z, 0, 0, 0);
    }
    // scatter C into accum: row=(lane>>4)*4+reg, col=ch*16+(lane&15)
#pragma unroll
    for (int ch = 0; ch < 4; ++ch) {
#pragma unroll
        for (int r = 0; r < 4; ++r) {
            accum_l[wid][((lane >> 4) * 4 + r) * COUT + ch * 16 + (lane & 15)] = cacc[ch][r];
        }
    }

    // --- candidate compaction (bitmap-passing probes) into LDS
    int cbase = 0;
    unsigned ovmask = 0;
#pragma unroll
    for (int t = 0; t < 7; ++t) {
        unsigned nlin = nlin_t[t];
        bool candq = try_t[t] && !((bmw[t] >> ((nlin >> 2) & 31u)) & 1u);
        unsigned long long m = __ballot(candq);
        if (candq) {
            int r = cbase + __popcll(m & ((1ull << lane) - 1ull));
            int off = (lane & 3) + 4 * t;
            int k = off + (off >= 13);
            if (r < CAND_CAP) {
                cand_l[wid][r] = ((unsigned long long)(((unsigned)pt << 5) | (unsigned)k) << 32)
                                 | (unsigned long long)nlin;
            } else {
                ovmask |= 1u << t;
            }
        }
        cbase += __popcll(m);
    }
    int ncand = cbase < CAND_CAP ? cbase : CAND_CAP;
    __asm__ __volatile__("s_waitcnt lgkmcnt(0)" ::: "memory");

    // --- parallel lookups: lane j resolves candidate j
    int hitbase = 0;
    int hni[2];
    unsigned hmeta[2];
    bool hov[2] = {false, false};
#pragma unroll
    for (int sub = 0; sub < 2; ++sub) {
        int j = sub * 64 + lane;
        int ni = -1;
        unsigned meta = 0;
        if (j < ncand) {
            unsigned long long e = cand_l[wid][j];
            meta = (unsigned)(e >> 32);
            ni = lookup(table, (unsigned)e);
        }
        unsigned long long m = __ballot(ni >= 0);
        if (ni >= 0) {
            int hr = hitbase + __popcll(m & ((1ull << lane) - 1ull));
            if (hr < HROWS) {
                hlist_l[wid][hr] = ((unsigned)ni << 9) | meta;
            } else {
                hov[sub] = true; hni[sub] = ni; hmeta[sub] = meta;
            }
        }
        hitbase += __popcll(m);
    }
    int hits = hitbase < HROWS ? hitbase : HROWS;
    __asm__ __volatile__("s_waitcnt lgkmcnt(0)" ::: "memory");

    // --- stage all hit rows as f16 (lane e handles row e>>2, seg e&3 = 8 ci)
    for (int e = lane; e < hits * 4; e += 64) {
        int r = e >> 2, s = e & 3;
        int ni = (int)(hlist_l[wid][r] >> 9);
        float4 u = *(const float4*)(feat + (size_t)ni * CIN + s * 8);
        float4 v = *(const float4*)(feat + (size_t)ni * CIN + s * 8 + 4);
        H2U q0, q1, q2, q3;
        q0.p = __builtin_amdgcn_cvt_pkrtz(u.x, u.y);
        q1.p = __builtin_amdgcn_cvt_pkrtz(u.z, u.w);
        q2.p = __builtin_amdgcn_cvt_pkrtz(v.x, v.y);
        q3.p = __builtin_amdgcn_cvt_pkrtz(v.z, v.w);
        *(uint4*)&rows_l[wid][r * 16 + s * 4] = make_uint4(q0.u, q1.u, q2.u, q3.u);
    }
    __asm__ __volatile__("s_waitcnt vmcnt(0) lgkmcnt(0)" ::: "memory");

    // --- hit taps: lane = co; 4x(ds_read_b128 + uint4 weight load + 4 fdot2)
    for (int j = 0; j < hits; ++j) {
        unsigned meta = hlist_l[wid][j] & 511u;
        int k = (int)(meta & 31u);
        int pt2 = (int)(meta >> 5);
        float s = 0.f;
#pragma unroll
        for (int g = 0; g < 4; ++g) {
            H8U fv, wv;
            fv.u4 = *(const uint4*)&rows_l[wid][j * 16 + g * 4];
            wv.u4 = wpack[(k * 4 + g) * 64 + lane];
            s = __builtin_amdgcn_fdot2(fv.h2[0], wv.h2[0], s, false);
            s = __builtin_amdgcn_fdot2(fv.h2[1], wv.h2[1], s, false);
            s = __builtin_amdgcn_fdot2(fv.h2[2], wv.h2[2], s, false);
            s = __builtin_amdgcn_fdot2(fv.h2[3], wv.h2[3], s, false);
        }
        accum_l[wid][pt2 * COUT + lane] += s;
    }

    // --- rare overflow paths (fp32 broadcast fallback)
    if (__builtin_expect(cbase > CAND_CAP, 0)) {
#pragma unroll
        for (int t = 0; t < 7; ++t) {
            unsigned long long m = __ballot((ovmask >> t) & 1u);
            while (m) {
                int src = __ffsll((unsigned long long)m) - 1;
                m &= m - 1;
                unsigned nlin = __shfl(nlin_t[t], src);
                int pt2 = src >> 2;
                int off = (src & 3) + 4 * t;
                int k = off + (off >= 13);
                int ni = lookup(table, nlin);
                if (ni >= 0) fb_tap(feat, weight, accum_l[wid], ni, pt2, k, lane);
            }
        }
    }
    if (__builtin_expect(hitbase > HROWS, 0)) {
#pragma unroll
        for (int sub = 0; sub < 2; ++sub) {
            unsigned long long m = __ballot(hov[sub]);
            while (m) {
                int src = __ffsll((unsigned long long)m) - 1;
                m &= m - 1;
                int ni = __shfl(hni[sub], src);
                unsigned meta = (unsigned)__shfl((int)hmeta[sub], src);
                fb_tap(feat, weight, accum_l[wid], ni, (int)((meta >> 5) & 15u),
                       (int)(meta & 31u), lane);
            }
        }
    }
    __asm__ __volatile__("s_waitcnt lgkmcnt(0)" ::: "memory");

    // --- coalesced store pass: dwordx4 per lane, 4 rows per iteration
    for (int e = lane; e < np * 16; e += 64) {
        int g = e >> 4, cq = e & 15;
        floatx4 v = *(const floatx4*)&accum_l[wid][g * COUT + cq * 4];
        __builtin_nontemporal_store(v, (floatx4*)&out[(size_t)(p0 + g) * COUT + cq * 4]);
    }
}

extern "C" void kernel_launch(void* const* d_in, const int* in_sizes, int n_in,
                              void* d_out, int out_size, void* d_ws, size_t ws_size,
                              hipStream_t stream) {
    const float* feat   = (const float*)d_in[0];   // [N, 32]
    const int4*  idx    = (const int4*)d_in[1];    // [N, 4] int32 (b,z,y,x)
    const float* weight = (const float*)d_in[2];   // [27, 32, 64]
    float* out = (float*)d_out;                    // [N, 64]
    int n = in_sizes[0] / CIN;

    unsigned char* base = (unsigned char*)d_ws;
    unsigned long long* table = (unsigned long long*)base;              // 8 MB
    unsigned* bitmap = (unsigned*)(base + (size_t)CAP * 8);             // 1.31 MB
    uint4* wpack = (uint4*)(base + (size_t)CAP * 8 + (size_t)BMWORDS * 4);  // 108 KB

    // One memset covers table (0xFF = EMPTY) and bitmap (0xFF = all-empty).
    hipMemsetAsync(table, 0xFF, (size_t)CAP * 8 + (size_t)BMWORDS * 4, stream);

    int bwork = n > WPACK_N ? n : WPACK_N;
    int bblocks = (bwork + 255) / 256;
    build_hash_kernel<<<bblocks, 256, 0, stream>>>(idx, n, table, bitmap, weight, wpack);

    int ppb = 4 * PPW;                             // 64 points per block
    int cblocks = (n + ppb - 1) / ppb;
    subm_conv_kernel<<<cblocks, 256, 0, stream>>>(feat, idx, weight, wpack, table,
                                                  bitmap, out, n);
}

// Round 16
// 180.870 us; speedup vs baseline: 1.0761x; 1.0278x over previous
//
#include <hip/hip_runtime.h>
#include <hip/hip_fp16.h>

// Submanifold sparse 3D conv, k=3, pad=1, no bias.
// Grid: 41 x 1024 x 1024, N=300000 active sites, C_in=32, C_out=64, fp32 I/O.
//
// R22 = R8 verbatim — the session's measured optimum (185.24 us total, conv
// dispatch 63.1 us, passed+profiled at R2 and reconfirmed by R18's null).
// R19/R20/R21 all hit infra failures (container crash / acquisition
// timeouts); this exact code has passed twice and never aborted.
// Resubmitted unchanged as the final artifact.
// Campaign summary (all single-variable A/Bs vs R8's conv=63.1):
//   R13 LDS diet -> 8 blocks/CU:        conv 84.0  (more residency = more
//                                        cache contention)
//   R14 persistent + 2-deep prefetch:   conv 82.0  (pipeline state spilled,
//                                        WRITE +16MB)
//   R15 exact 1-bit/voxel bitmap:       conv 66.5  (5.25MB > 4MiB/XCD L2,
//                                        FETCH 52->100MB)
//   R17 fat waves PPW=32:               conv 71.5  (occupancy 32->21%)
//   R18 quad bitmap (half FP rate):     conv 63.4  (NULL - lookup FP rate
//                                        was never the spine)
// Conclusion: conv is at a 5-experiment local optimum; the cost is the
// per-wave scattered-VMEM request stream (~450 distinct cachelines per wave
// through one L1 across probe/lookup/stage), invariant under concurrency,
// pipelining, and filter-precision changes. Counters at optimum: VALUBusy
// 23%, MfmaUtil 0.7%, HBM 26%, Occupancy 32%, FETCH 52MB (= ideal),
// WRITE 75MB (= ideal), VGPR 52, 0 spills.

#define ZD 41
#define YD 1024
#define XD 1024

constexpr int CIN = 32;
constexpr int COUT = 64;
constexpr unsigned HASH_BITS = 20;               // 2^20 slots, load ~0.29
constexpr unsigned CAP = 1u << HASH_BITS;
constexpr unsigned GROUP_BITS = HASH_BITS - 3;   // octet groups
constexpr unsigned long long EMPTY = ~0ull;
constexpr unsigned NVOX = ZD * YD * XD;
constexpr unsigned NOCT = NVOX / 8;
constexpr unsigned BMWORDS = (NOCT + 31) / 32;   // 656 KB (bit=1: EMPTY)
constexpr int PPW = 16;                          // points per wave
constexpr int CAND_CAP = 96;                     // candidate slots per wave
constexpr int HROWS = 48;                        // staged hit rows per wave
constexpr int WPACK_N = 27 * 4 * 64;             // uint4 entries

typedef _Float16 half2_t __attribute__((ext_vector_type(2)));
typedef _Float16 half8_t __attribute__((ext_vector_type(8)));
typedef __fp16 pk2_t __attribute__((ext_vector_type(2)));   // cvt_pkrtz result type
typedef float floatx4 __attribute__((ext_vector_type(4)));

union H2U { pk2_t p; half2_t h; unsigned u; };
union H8U { half8_t v; half2_t h2[4]; pk2_t p2[4]; uint4 u4; };

// --- packed per-round neighbor-delta immediates -----------------------------
// Round t, lane slot j4 = lane&3 handles off = 4t+j4 (off<26), k = off+(off>=13).
// Field (6 bits): (dx+1) | (dy+1)<<2 | (dz+1)<<4.
__host__ __device__ constexpr unsigned pack6(int k) {
    return (unsigned)((k % 3) | (((k / 3) % 3) << 2) | ((k / 9) << 4));
}
__host__ __device__ constexpr unsigned cw_round(int t) {
    unsigned w = 0;
    for (int j4 = 0; j4 < 4; ++j4) {
        int off = 4 * t + j4;
        if (off < 26) {
            int k = off + (off >= 13);
            w |= pack6(k) << (6 * j4);
        }
    }
    return w;
}

__device__ __forceinline__ unsigned hash_slot(unsigned lin) {
    unsigned gh = ((lin >> 3) * 2654435761u) >> (32 - GROUP_BITS);
    return (gh << 3) | (lin & 7u);
}

__global__ void build_hash_kernel(const int4* __restrict__ idx, int n,
                                  unsigned long long* __restrict__ table,
                                  unsigned* __restrict__ bitmap,
                                  const float* __restrict__ weight,
                                  uint4* __restrict__ wpack) {
    int i = blockIdx.x * blockDim.x + threadIdx.x;
    // --- pack fp32 weights -> f16 pairs: wpack[(k*4+g)*64+co] = 8 f16 (ci 8g..8g+7)
    if (i < WPACK_N) {
        int co = i & 63, g = (i >> 6) & 3, k = i >> 8;
        const float* b = weight + k * (CIN * COUT) + (8 * g) * COUT + co;
        H2U p0, p1, p2, p3;
        p0.p = __builtin_amdgcn_cvt_pkrtz(b[0 * COUT], b[1 * COUT]);
        p1.p = __builtin_amdgcn_cvt_pkrtz(b[2 * COUT], b[3 * COUT]);
        p2.p = __builtin_amdgcn_cvt_pkrtz(b[4 * COUT], b[5 * COUT]);
        p3.p = __builtin_amdgcn_cvt_pkrtz(b[6 * COUT], b[7 * COUT]);
        wpack[i] = make_uint4(p0.u, p1.u, p2.u, p3.u);
    }
    if (i >= n) return;
    int4 c = idx[i];                             // (b, z, y, x)
    unsigned lin = (unsigned)(c.y * (YD * XD) + c.z * XD + c.w);
    unsigned g = lin >> 3;
    atomicAnd(&bitmap[g >> 5], ~(1u << (g & 31u)));   // clear bit = occupied
    unsigned long long packed = ((unsigned long long)(unsigned)i << 32) | (unsigned long long)lin;
    unsigned h = hash_slot(lin);
    while (atomicCAS(&table[h], EMPTY, packed) != EMPTY) {
        h = (h + 1) & (CAP - 1);                 // coords unique -> no dup check
    }
}

__device__ __forceinline__ int lookup(const unsigned long long* __restrict__ table,
                                      unsigned lin) {
    unsigned h = hash_slot(lin);
    while (true) {
        unsigned long long s = table[h];
        if (s == EMPTY) return -1;
        if ((unsigned)s == lin) return (int)(s >> 32);
        h = (h + 1) & (CAP - 1);
    }
}

// fp32 broadcast fallback tap (rare overflow paths) into LDS accum.
__device__ __forceinline__ void fb_tap(const float* __restrict__ feat,
                                       const float* __restrict__ weight,
                                       float* __restrict__ acc,
                                       int ni, int pt, int k, int lane) {
    const float4* fr = (const float4*)(feat + (size_t)ni * CIN);
    const float* wk = weight + k * (CIN * COUT) + lane;
    float s0 = 0.f, s1 = 0.f, s2 = 0.f, s3 = 0.f;
#pragma unroll
    for (int q = 0; q < 8; ++q) {
        float4 f = fr[q];
        s0 = fmaf(f.x, wk[(4 * q + 0) * COUT], s0);
        s1 = fmaf(f.y, wk[(4 * q + 1) * COUT], s1);
        s2 = fmaf(f.z, wk[(4 * q + 2) * COUT], s2);
        s3 = fmaf(f.w, wk[(4 * q + 3) * COUT], s3);
    }
    acc[pt * COUT + lane] += (s0 + s1) + (s2 + s3);
}

__global__ __launch_bounds__(256, 4) void subm_conv_kernel(
    const float* __restrict__ feat, const int4* __restrict__ idx,
    const float* __restrict__ weight, const uint4* __restrict__ wpack,
    const unsigned long long* __restrict__ table,
    const unsigned* __restrict__ bitmap, float* __restrict__ out, int n) {
    __shared__ unsigned rows_l[4][HROWS * 16];          // 12 KB: f16 rows (16 u32 each)
    __shared__ float accum_l[4][PPW * COUT];            // 16 KB
    __shared__ unsigned long long cand_l[4][CAND_CAP];  // 3 KB
    __shared__ unsigned hlist_l[4][HROWS];              // 768 B

    int wid = threadIdx.x >> 6;
    int lane = threadIdx.x & 63;
    int p0 = (blockIdx.x * 4 + wid) * PPW;
    if (p0 >= n) return;
    int np = min(PPW, n - p0);

    // --- coords: 4 lanes per point
    int pt = lane >> 2;
    int4 c = idx[p0 + (pt < np ? pt : 0)];

    // --- bitmap words for 7 probe rounds (independent, issued early)
    int sh6 = (lane & 3) * 6;
    bool ptok = (pt < np);
    unsigned nlin_t[7];
    unsigned bmw[7];
    bool try_t[7];
#pragma unroll
    for (int t = 0; t < 7; ++t) {
        unsigned w = (cw_round(t) >> sh6) & 63u;
        int nz = c.y + (int)(w >> 4) - 1;
        int ny = c.z + (int)((w >> 2) & 3u) - 1;
        int nx = c.w + (int)(w & 3u) - 1;
        bool ok = ptok && (unsigned)nz < (unsigned)ZD && (unsigned)ny < (unsigned)YD &&
                  (unsigned)nx < (unsigned)XD;
        if (t == 6) ok = ok && ((lane & 3) < 2);        // offs 26,27 don't exist
        unsigned nlin = ok ? ((((unsigned)nz << 10) + (unsigned)ny) << 10) + (unsigned)nx : 0u;
        nlin_t[t] = nlin;
        try_t[t] = ok;
        bmw[t] = ok ? bitmap[nlin >> 8] : ~0u;          // bit=1 means empty
    }

    // --- center tap via MFMA f16: D[pt][co] = feat[p0+pt][:] @ W13
    int arow = lane & 15, aq = lane >> 4;               // A: m=lane&15, k=aq*8+j
    int rowp = p0 + (arow < np ? arow : np - 1);
    float4 af0 = *(const float4*)(feat + (size_t)rowp * CIN + aq * 8);
    float4 af1 = *(const float4*)(feat + (size_t)rowp * CIN + aq * 8 + 4);
    H8U afrag;
    afrag.p2[0] = __builtin_amdgcn_cvt_pkrtz(af0.x, af0.y);
    afrag.p2[1] = __builtin_amdgcn_cvt_pkrtz(af0.z, af0.w);
    afrag.p2[2] = __builtin_amdgcn_cvt_pkrtz(af1.x, af1.y);
    afrag.p2[3] = __builtin_amdgcn_cvt_pkrtz(af1.z, af1.w);

    floatx4 cacc[4];
#pragma unroll
    for (int ch = 0; ch < 4; ++ch) {
        H8U bfrag;                                       // B: k=aq*8+j, n=lane&15
        bfrag.u4 = wpack[(13 * 4 + aq) * 64 + ch * 16 + (lane & 15)];
        floatx4 z = {0.f, 0.f, 0.f, 0.f};
        cacc[ch] = __builtin_amdgcn_mfma_f32_16x16x32_f16(afrag.v, bfrag.v, z, 0, 0, 0);
    }
    // scatter C into accum: row=(lane>>4)*4+reg, col=ch*16+(lane&15)
#pragma unroll
    for (int ch = 0; ch < 4; ++ch) {
#pragma unroll
        for (int r = 0; r < 4; ++r) {
            accum_l[wid][((lane >> 4) * 4 + r) * COUT + ch * 16 + (lane & 15)] = cacc[ch][r];
        }
    }

    // --- candidate compaction (bitmap-passing probes) into LDS
    int cbase = 0;
    unsigned ovmask = 0;
#pragma unroll
    for (int t = 0; t < 7; ++t) {
        unsigned nlin = nlin_t[t];
        bool candq = try_t[t] && !((bmw[t] >> ((nlin >> 3) & 31u)) & 1u);
        unsigned long long m = __ballot(candq);
        if (candq) {
            int r = cbase + __popcll(m & ((1ull << lane) - 1ull));
            int off = (lane & 3) + 4 * t;
            int k = off + (off >= 13);
            if (r < CAND_CAP) {
                cand_l[wid][r] = ((unsigned long long)(((unsigned)pt << 5) | (unsigned)k) << 32)
                                 | (unsigned long long)nlin;
            } else {
                ovmask |= 1u << t;
            }
        }
        cbase += __popcll(m);
    }
    int ncand = cbase < CAND_CAP ? cbase : CAND_CAP;
    __asm__ __volatile__("s_waitcnt lgkmcnt(0)" ::: "memory");

    // --- parallel lookups: lane j resolves candidate j
    int hitbase = 0;
    int hni[2];
    unsigned hmeta[2];
    bool hov[2] = {false, false};
#pragma unroll
    for (int sub = 0; sub < 2; ++sub) {
        int j = sub * 64 + lane;
        int ni = -1;
        unsigned meta = 0;
        if (j < ncand) {
            unsigned long long e = cand_l[wid][j];
            meta = (unsigned)(e >> 32);
            ni = lookup(table, (unsigned)e);
        }
        unsigned long long m = __ballot(ni >= 0);
        if (ni >= 0) {
            int hr = hitbase + __popcll(m & ((1ull << lane) - 1ull));
            if (hr < HROWS) {
                hlist_l[wid][hr] = ((unsigned)ni << 9) | meta;
            } else {
                hov[sub] = true; hni[sub] = ni; hmeta[sub] = meta;
            }
        }
        hitbase += __popcll(m);
    }
    int hits = hitbase < HROWS ? hitbase : HROWS;
    __asm__ __volatile__("s_waitcnt lgkmcnt(0)" ::: "memory");

    // --- stage all hit rows as f16 (lane e handles row e>>2, seg e&3 = 8 ci)
    for (int e = lane; e < hits * 4; e += 64) {
        int r = e >> 2, s = e & 3;
        int ni = (int)(hlist_l[wid][r] >> 9);
        float4 u = *(const float4*)(feat + (size_t)ni * CIN + s * 8);
        float4 v = *(const float4*)(feat + (size_t)ni * CIN + s * 8 + 4);
        H2U q0, q1, q2, q3;
        q0.p = __builtin_amdgcn_cvt_pkrtz(u.x, u.y);
        q1.p = __builtin_amdgcn_cvt_pkrtz(u.z, u.w);
        q2.p = __builtin_amdgcn_cvt_pkrtz(v.x, v.y);
        q3.p = __builtin_amdgcn_cvt_pkrtz(v.z, v.w);
        *(uint4*)&rows_l[wid][r * 16 + s * 4] = make_uint4(q0.u, q1.u, q2.u, q3.u);
    }
    __asm__ __volatile__("s_waitcnt vmcnt(0) lgkmcnt(0)" ::: "memory");

    // --- hit taps: lane = co; 4x(ds_read_b128 + uint4 weight load + 4 fdot2)
    for (int j = 0; j < hits; ++j) {
        unsigned meta = hlist_l[wid][j] & 511u;
        int k = (int)(meta & 31u);
        int pt2 = (int)(meta >> 5);
        float s = 0.f;
#pragma unroll
        for (int g = 0; g < 4; ++g) {
            H8U fv, wv;
            fv.u4 = *(const uint4*)&rows_l[wid][j * 16 + g * 4];
            wv.u4 = wpack[(k * 4 + g) * 64 + lane];
            s = __builtin_amdgcn_fdot2(fv.h2[0], wv.h2[0], s, false);
            s = __builtin_amdgcn_fdot2(fv.h2[1], wv.h2[1], s, false);
            s = __builtin_amdgcn_fdot2(fv.h2[2], wv.h2[2], s, false);
            s = __builtin_amdgcn_fdot2(fv.h2[3], wv.h2[3], s, false);
        }
        accum_l[wid][pt2 * COUT + lane] += s;
    }

    // --- rare overflow paths (fp32 broadcast fallback)
    if (__builtin_expect(cbase > CAND_CAP, 0)) {
#pragma unroll
        for (int t = 0; t < 7; ++t) {
            unsigned long long m = __ballot((ovmask >> t) & 1u);
            while (m) {
                int src = __ffsll((unsigned long long)m) - 1;
                m &= m - 1;
                unsigned nlin = __shfl(nlin_t[t], src);
                int pt2 = src >> 2;
                int off = (src & 3) + 4 * t;
                int k = off + (off >= 13);
                int ni = lookup(table, nlin);
                if (ni >= 0) fb_tap(feat, weight, accum_l[wid], ni, pt2, k, lane);
            }
        }
    }
    if (__builtin_expect(hitbase > HROWS, 0)) {
#pragma unroll
        for (int sub = 0; sub < 2; ++sub) {
            unsigned long long m = __ballot(hov[sub]);
            while (m) {
                int src = __ffsll((unsigned long long)m) - 1;
                m &= m - 1;
                int ni = __shfl(hni[sub], src);
                unsigned meta = (unsigned)__shfl((int)hmeta[sub], src);
                fb_tap(feat, weight, accum_l[wid], ni, (int)((meta >> 5) & 15u),
                       (int)(meta & 31u), lane);
            }
        }
    }
    __asm__ __volatile__("s_waitcnt lgkmcnt(0)" ::: "memory");

    // --- coalesced store pass: dwordx4 per lane, 4 rows per iteration
    for (int e = lane; e < np * 16; e += 64) {
        int g = e >> 4, cq = e & 15;
        floatx4 v = *(const floatx4*)&accum_l[wid][g * COUT + cq * 4];
        __builtin_nontemporal_store(v, (floatx4*)&out[(size_t)(p0 + g) * COUT + cq * 4]);
    }
}

extern "C" void kernel_launch(void* const* d_in, const int* in_sizes, int n_in,
                              void* d_out, int out_size, void* d_ws, size_t ws_size,
                              hipStream_t stream) {
    const float* feat   = (const float*)d_in[0];   // [N, 32]
    const int4*  idx    = (const int4*)d_in[1];    // [N, 4] int32 (b,z,y,x)
    const float* weight = (const float*)d_in[2];   // [27, 32, 64]
    float* out = (float*)d_out;                    // [N, 64]
    int n = in_sizes[0] / CIN;

    unsigned char* base = (unsigned char*)d_ws;
    unsigned long long* table = (unsigned long long*)base;              // 8 MB
    unsigned* bitmap = (unsigned*)(base + (size_t)CAP * 8);             // 656 KB
    uint4* wpack = (uint4*)(base + (size_t)CAP * 8 + (size_t)BMWORDS * 4);  // 108 KB

    // One memset covers table (0xFF = EMPTY) and bitmap (0xFF = all-empty).
    hipMemsetAsync(table, 0xFF, (size_t)CAP * 8 + (size_t)BMWORDS * 4, stream);

    int bwork = n > WPACK_N ? n : WPACK_N;
    int bblocks = (bwork + 255) / 256;
    build_hash_kernel<<<bblocks, 256, 0, stream>>>(idx, n, table, bitmap, weight, wpack);

    int ppb = 4 * PPW;                             // 64 points per block
    int cblocks = (n + ppb - 1) / ppb;
    subm_conv_kernel<<<cblocks, 256, 0, stream>>>(feat, idx, weight, wpack, table,
                                                  bitmap, out, n);
}